// Round 9
// baseline (168.071 us; speedup 1.0000x reference)
//
#include <hip/hip_runtime.h>
#include <hip/hip_fp16.h>

// Idealizer: torsion angles + backbone frames -> atom14 coordinates.
// 128 threads/block; EACH THREAD computes TWO residues (tid, tid+128) of a
// 256-residue tile (ILP-2: two independent dep chains per wave). Atoms 4..13
// go to an LDS tile; copy-out is coalesced float2 (backbone from bb).
//
// Journal:
// R1 93us reg-buffered. R2 forced 64 VGPR -> spill 159us. R4 scattered dword
// stores -> WRITE 266MB. R5 LDS tile -> clean 82MB, 63us. R6 4 blk/CU flat.
// R7 -15% VALU, 3 blk/CU flat: dur ~ work/issue_eff, need both.
// R8 56us: bank fix verified (1.9M->0.6M). BUT LDS 40960x4 = exactly 160KiB
//     -> reservation kicked one block out (occupancy 24.6% ~= 3 blk/CU).
// R9: LDS 40212 (df group-major 8064 B, meta row 17 dwords: lit-fp16+gpk+
//     mbit) -> real 4 blk/CU; ILP-2 branch-free dual-residue body.

struct F3 { float x, y, z; };

__device__ __forceinline__ F3 f3sub(F3 a, F3 b) { return {a.x-b.x, a.y-b.y, a.z-b.z}; }
__device__ __forceinline__ F3 f3cross(F3 a, F3 b) {
    return {a.y*b.z - a.z*b.y, a.z*b.x - a.x*b.z, a.x*b.y - a.y*b.x};
}
__device__ __forceinline__ float f3dot(F3 a, F3 b) { return a.x*b.x + a.y*b.y + a.z*b.z; }

__device__ __forceinline__ void dihedral_from(F3 A, F3 B, F3 mid,
                                              float& s, float& c) {
    float x = f3dot(A, B);
    F3 w = f3cross(A, B);
    float y = f3dot(w, mid) * rsqrtf(fmaxf(f3dot(mid, mid), 1e-30f));
    float r2 = x * x + y * y;
    float rinv = rsqrtf(r2);
    bool ok = r2 > 1e-24f;
    s = ok ? y * rinv : 0.0f;   // atan2(0,0)=0 -> angle 0
    c = ok ? x * rinv : 1.0f;
}

#define DF_G      252   // dwords per group block: 21 aa x 12 (rows 16B-aligned,
                        // aai-stride 12 -> 8 bank positions)
#define META      17    // dwords per aa: 15 x half2 lit + gpk + mbit (odd stride)
#define OT_STRIDE 30    // output tile row: atoms 4..13

__device__ __forceinline__ void compute_one(
    int i, int row, int n,
    const int* __restrict__ aa, const float* __restrict__ bb,
    const float* __restrict__ tor,
    const float* __restrict__ s_df, const unsigned* __restrict__ s_meta,
    float* __restrict__ s_ot)
{
    const int ic = (i < n - 1) ? i : (n - 1);   // clamped (garbage lanes ok)

    // ---- own residue backbone (N, CA, C = floats 0..8) ----
    const float4* bb4 = (const float4*)bb;
    float4 q0 = bb4[ic * 3 + 0];   // N.xyz, CA.x
    float4 q1 = bb4[ic * 3 + 1];   // CA.yz, C.xy
    float Cz  = bb[ic * 12 + 8];
    F3 Np  = {q0.x, q0.y, q0.z};
    F3 CAp = {q0.w, q1.x, q1.y};
    F3 Cp  = {q1.z, q1.w, Cz};

    // ---- neighbors (clamped; boundary angles overridden below) ----
    const int im = (ic > 0)     ? ic - 1 : 0;
    const int ip = (ic < n - 1) ? ic + 1 : 0;
    F3 Cm = { bb[im * 12 + 6], bb[im * 12 + 7], bb[im * 12 + 8] };
    float4 r0 = bb4[ip * 3 + 0];
    float2 r1 = ((const float2*)bb)[ip * 6 + 2];
    F3 Nn  = {r0.x, r0.y, r0.z};
    F3 CAn = {r0.w, r1.x, r1.y};

    // ---- backbone dihedrals via shared bond crosses ----
    F3 u1 = f3sub(Np, Cm);
    F3 u2 = f3sub(CAp, Np);
    F3 u3 = f3sub(Cp, CAp);
    F3 u4 = f3sub(Nn, Cp);
    F3 u5 = f3sub(CAn, Nn);
    F3 c12 = f3cross(u1, u2), c23 = f3cross(u2, u3);
    F3 c34 = f3cross(u3, u4), c45 = f3cross(u4, u5);
    float s_ph, c_ph, s_ps, c_ps, s_om, c_om;
    dihedral_from(c12, c23, u2, s_ph, c_ph);   // phi
    dihedral_from(c23, c34, u3, s_ps, c_ps);   // psi
    dihedral_from(c34, c45, u4, s_om, c_om);   // omega
    if (ic == 0)     { s_ph = 0.0f; c_ph = 1.0f; }
    if (ic == n - 1) { s_ps = 0.0f; c_ps = 1.0f; s_om = 0.0f; c_om = 1.0f; }

    // ---- backbone frame from reference (N, CA, C) ----
    const float eps = 1e-20f;
    F3 nv = f3sub(Np, CAp);
    F3 cv = f3sub(Cp, CAp);
    float cx = cv.x, cy = cv.y, cz2 = cv.z;
    float d2xy  = cx * cx + cy * cy;
    float inrm  = rsqrtf(eps + d2xy);
    float s1 = -cy * inrm, c1 = cx * inrm;
    float inrm2 = rsqrtf(eps + d2xy + cz2 * cz2);
    float s2v = cz2 * inrm2, c2v = sqrtf(d2xy) * inrm2;
    float Rc00 = c2v * c1,  Rc01 = -c2v * s1, Rc02 = s2v;
    float Rc10 = s1,        Rc11 = c1,        Rc12 = 0.0f;
    float Rc20 = -s2v * c1, Rc21 = s2v * s1,  Rc22 = c2v;
    float n2y = Rc10 * nv.x + Rc11 * nv.y + Rc12 * nv.z;
    float n2z = Rc20 * nv.x + Rc21 * nv.y + Rc22 * nv.z;
    float inrm3 = rsqrtf(eps + n2y * n2y + n2z * n2z);
    float sn = -n2z * inrm3, cn = n2y * inrm3;
    float M10 = cn * Rc10 - sn * Rc20, M11 = cn * Rc11 - sn * Rc21, M12 = cn * Rc12 - sn * Rc22;
    float M20 = sn * Rc10 + cn * Rc20, M21 = sn * Rc11 + cn * Rc21;
    float M22 = sn * Rc12 + cn * Rc22;
    float B00 = Rc00, B01 = M10, B02 = M20;
    float B10 = Rc01, B11 = M11, B12 = M21;
    float B20 = Rc02, B21 = M12, B22 = M22;

    // ---- per-frame sin/cos: [identity, omega, phi, psi, tor0..3] ----
    float4 tv = ((const float4*)tor)[ic];
    float sang[8], cang[8];
    sang[0] = 0.0f; cang[0] = 1.0f;
    sang[1] = s_om; cang[1] = c_om;
    sang[2] = s_ph; cang[2] = c_ph;
    sang[3] = s_ps; cang[3] = c_ps;
    __sincosf(tv.x, &sang[4], &cang[4]);
    __sincosf(tv.y, &sang[5], &cang[5]);
    __sincosf(tv.z, &sang[6], &cang[6]);
    __sincosf(tv.w, &sang[7], &cang[7]);

    const int aai = aa[ic];
    const unsigned* mrow = &s_meta[aai * META];
    const unsigned gpk  = mrow[15];
    const unsigned mbit = mrow[16];

    // hoist lit positions (fp16, packed in meta row)
    float la[30];
    #pragma unroll
    for (int k = 0; k < 15; k++) {
        unsigned u = mrow[k];
        __half2 h = *(__half2*)&u;
        float2 t = __half22float2(h);
        la[2*k] = t.x; la[2*k+1] = t.y;
    }

    float v[30];
    #pragma unroll
    for (int k = 0; k < 30; k++) v[k] = 0.0f;

    // ---- group chain in LOCAL (backbone-relative) coords ----
    float L00, L01, L02, L10, L11, L12, L20, L21, L22, Lx, Ly, Lz;
    const float* dfa = s_df + aai * 12;
    #pragma unroll
    for (int g = 0; g < 8; g++) {
        const float4* dfr = (const float4*)(dfa + g * DF_G);
        float4 d0 = dfr[0], d1 = dfr[1], d2 = dfr[2];  // rows (m,m,m,t)
        float sA = sang[g], cA = cang[g];
        float f00 = d0.x, f01 = cA * d0.y + sA * d0.z, f02 = cA * d0.z - sA * d0.y;
        float f10 = d1.x, f11 = cA * d1.y + sA * d1.z, f12 = cA * d1.z - sA * d1.y;
        float f20 = d2.x, f21 = cA * d2.y + sA * d2.z, f22 = cA * d2.z - sA * d2.y;
        if (g <= 4) {
            L00 = f00; L01 = f01; L02 = f02;
            L10 = f10; L11 = f11; L12 = f12;
            L20 = f20; L21 = f21; L22 = f22;
            Lx = d0.w; Ly = d1.w; Lz = d2.w;
        } else {
            float n00 = L00 * f00 + L01 * f10 + L02 * f20;
            float n01 = L00 * f01 + L01 * f11 + L02 * f21;
            float n02 = L00 * f02 + L01 * f12 + L02 * f22;
            float n10 = L10 * f00 + L11 * f10 + L12 * f20;
            float n11 = L10 * f01 + L11 * f11 + L12 * f21;
            float n12 = L10 * f02 + L11 * f12 + L12 * f22;
            float n20 = L20 * f00 + L21 * f10 + L22 * f20;
            float n21 = L20 * f01 + L21 * f11 + L22 * f21;
            float n22 = L20 * f02 + L21 * f12 + L22 * f22;
            float ntx = L00 * d0.w + L01 * d1.w + L02 * d2.w + Lx;
            float nty = L10 * d0.w + L11 * d1.w + L12 * d2.w + Ly;
            float ntz = L20 * d0.w + L21 * d1.w + L22 * d2.w + Lz;
            L00 = n00; L01 = n01; L02 = n02;
            L10 = n10; L11 = n11; L12 = n12;
            L20 = n20; L21 = n21; L22 = n22;
            Lx = ntx; Ly = nty; Lz = ntz;
        }

        // dense branchless select
        #pragma unroll
        for (int a = 0; a < 10; a++) {
            bool sel = ((gpk >> (3 * a)) & 7u) == (unsigned)g;
            float qx = fmaf(L00, la[3*a], fmaf(L01, la[3*a+1], fmaf(L02, la[3*a+2], Lx)));
            float qy = fmaf(L10, la[3*a], fmaf(L11, la[3*a+1], fmaf(L12, la[3*a+2], Ly)));
            float qz = fmaf(L20, la[3*a], fmaf(L21, la[3*a+1], fmaf(L22, la[3*a+2], Lz)));
            v[3*a]   = sel ? qx : v[3*a];
            v[3*a+1] = sel ? qy : v[3*a+1];
            v[3*a+2] = sel ? qz : v[3*a+2];
        }
    }

    // ---- backbone frame + mask once per atom ----
    #pragma unroll
    for (int a = 0; a < 10; a++) {
        float mk = ((mbit >> a) & 1u) ? 1.0f : 0.0f;
        float qx = v[3*a], qy = v[3*a+1], qz = v[3*a+2];
        v[3*a]   = mk * fmaf(B00, qx, fmaf(B01, qy, fmaf(B02, qz, CAp.x)));
        v[3*a+1] = mk * fmaf(B10, qx, fmaf(B11, qy, fmaf(B12, qz, CAp.y)));
        v[3*a+2] = mk * fmaf(B20, qx, fmaf(B21, qy, fmaf(B22, qz, CAp.z)));
    }

    // ---- tile row write: 15 x ds_write_b64 ----
    float2* so2 = (float2*)&s_ot[row * OT_STRIDE];
    #pragma unroll
    for (int k = 0; k < 15; k++)
        so2[k] = make_float2(v[2*k], v[2*k+1]);
}

__global__ __launch_bounds__(128) void idealizer_kernel(
    const int*   __restrict__ aa,       // (n,)
    const float* __restrict__ bb,       // (n,4,3)
    const float* __restrict__ tor,      // (n,4)
    const float* __restrict__ dframes,  // (21,8,4,4)
    const int*   __restrict__ gidx,     // (21,14)
    const float* __restrict__ amask,    // (21,14)
    const float* __restrict__ lit,      // (21,14,3)
    float*       __restrict__ out,      // (n,14,3)
    int n)
{
    __shared__ __align__(16) float    s_ot[256 * OT_STRIDE];  // 30720 B
    __shared__ __align__(16) float    s_df[8 * DF_G];         //  8064 B
    __shared__ __align__(8)  unsigned s_meta[21 * META];      //  1428 B
    // total 40212 B -> alloc <= 40448 -> 4 blocks/CU with slack

    const int tid = threadIdx.x;
    // stage df group-major: s_df[g*252 + a*12 + e] = dframes[(a*8+g)*16+e], e<12
    for (int j = tid; j < 8 * DF_G; j += 128) {
        int g = j / DF_G; int rme = j - g * DF_G;
        int a = rme / 12; int e = rme - a * 12;
        s_df[j] = dframes[(a * 8 + g) * 16 + e];
    }
    // stage lit as half2 pairs into meta rows
    for (int j = tid; j < 21 * 15; j += 128) {
        int a = j / 15, k = j - a * 15;
        float x = lit[a * 42 + 12 + 2 * k];
        float y = lit[a * 42 + 12 + 2 * k + 1];
        __half2 h = __floats2half2_rn(x, y);
        s_meta[a * META + k] = *(unsigned*)&h;
    }
    if (tid < 21) {
        unsigned gp = 0, mb = 0;
        #pragma unroll
        for (int a = 0; a < 10; a++) {
            gp |= ((unsigned)gidx[tid * 14 + 4 + a]) << (3 * a);
            mb |= (amask[tid * 14 + 4 + a] != 0.0f ? 1u : 0u) << a;
        }
        s_meta[tid * META + 15] = gp;
        s_meta[tid * META + 16] = mb;
    }
    __syncthreads();

    const int i0 = blockIdx.x * 256;
    // ILP-2: two independent residue chains per thread, branch-free bodies
    compute_one(i0 + tid,       tid,       n, aa, bb, tor, s_df, s_meta, s_ot);
    compute_one(i0 + tid + 128, tid + 128, n, aa, bb, tor, s_df, s_meta, s_ot);

    __syncthreads();

    // ---- coalesced copy-out, division-free (step 128 = 6*21 + 2) ----
    int m = n - i0; if (m > 256) m = 256;
    const int cnt2 = m * 21;
    float2* gout = (float2*)(out + (size_t)i0 * 42);
    const float2* bbt = (const float2*)(bb + (size_t)i0 * 12);
    int r = tid / 21;
    int j = tid - r * 21;
    for (int off = tid; off < cnt2; off += 128) {
        int bi = (j < 6) ? (r * 6 + j) : 0;
        float2 gval = bbt[bi];
        int tj = (j < 6) ? 0 : (j - 6);
        const float* tp = &s_ot[r * OT_STRIDE + 2 * tj];
        float2 lval = make_float2(tp[0], tp[1]);
        gout[off] = (j < 6) ? gval : lval;
        r += 6; j += 2;
        if (j >= 21) { j -= 21; r += 1; }
    }
}

extern "C" void kernel_launch(void* const* d_in, const int* in_sizes, int n_in,
                              void* d_out, int out_size, void* d_ws, size_t ws_size,
                              hipStream_t stream) {
    const int*   aa  = (const int*)d_in[0];
    const float* bb  = (const float*)d_in[1];
    const float* tor = (const float*)d_in[2];
    const float* df  = (const float*)d_in[3];
    const int*   gi  = (const int*)d_in[4];
    const float* am  = (const float*)d_in[5];
    const float* lp  = (const float*)d_in[6];
    float* outp = (float*)d_out;
    const int n = in_sizes[0];
    const int blocks = (n + 255) / 256;   // one 256-residue tile per block
    idealizer_kernel<<<blocks, 128, 0, stream>>>(aa, bb, tor, df, gi, am, lp, outp, n);
}